// Round 13
// baseline (304.203 us; speedup 1.0000x reference)
//
#include <hip/hip_runtime.h>
#include <cfloat>

#define B_ 8
#define C_ 64
#define N_ 4096
#define K_ 20
#define MARGIN 0.08f
#define CAP 64
#define GRID_ 512

typedef float f32x4v  __attribute__((ext_vector_type(4)));
typedef float f32x16v __attribute__((ext_vector_type(16)));
typedef _Float16 f16x8 __attribute__((ext_vector_type(8)));
typedef unsigned long long u64;

// ws layout (bytes):
//   xxn : B*N floats (= -xx/2, fp64-accumulated)  @ 0
//   idx : B*N*20 ints                             @ 131072
//   qg  : B*N*128 floats [b][m][o2]               @ 2752512  (16 MB)
//         -- ALSO used (during scan) as bufg: B*N*CAP u64 = 16 MB exact.
//         Per-block self-aliasing overlay (validated r5).
//   P0  : [b][seg=c/8][m][j=c%8] f16 limb0        @ 19529728 (4 MB)
//   P1  : limb1 (scale 2^-12)                     @ 23724032 (4 MB)
#define OFF_IDX 131072
#define OFF_QG  2752512
#define OFF_P0  19529728
#define OFF_P1  23724032

// Device-wide barrier counter. Module global (.bss, zero-init, persistent):
// never aliased by any data write (r12's bug: ctr in `out` was clobbered by
// out-phase stores, breaking graph-replay runs -> hang). Monotonic rounds:
// each COMPLETE launch adds 2*GRID_ = 1024 == 0 (mod 512), so replays stay
// aligned with no reset traffic.
__device__ unsigned g_ctr;

// async global->LDS, 16B per lane. Validated rounds 1-10.
__device__ __forceinline__ void gll16(const void* g, void* l) {
    __builtin_amdgcn_global_load_lds(
        (const __attribute__((address_space(1))) unsigned int*)g,
        (__attribute__((address_space(3))) unsigned int*)l, 16, 0, 0);
}

// Graph-capturable device-wide barrier. Precondition: all GRID_ blocks
// co-resident (512 blocks x 67328B LDS = exactly 2/CU x 256 CU; VGPR<=128).
// __syncthreads drains this block's stores to L2; release fence (agent) =
// L2 writeback; acquire fence (agent) = invalidate (Guideline 16 pattern).
__device__ __forceinline__ void gbarrier() {
    __syncthreads();
    if (threadIdx.x == 0) {
        __threadfence();   // release: this XCD's dirty L2 -> coherence point
        unsigned t = __hip_atomic_fetch_add(&g_ctr, 1u, __ATOMIC_ACQ_REL,
                                            __HIP_MEMORY_SCOPE_AGENT);
        unsigned target = (t & ~(unsigned)(GRID_ - 1)) + GRID_;
        while (__hip_atomic_load(&g_ctr, __ATOMIC_RELAXED,
                                 __HIP_MEMORY_SCOPE_AGENT) < target)
            __builtin_amdgcn_s_sleep(8);
        __threadfence();   // acquire: invalidate stale lines
    }
    __syncthreads();
}

// 1-limb approx score (phase 1): s = A0·B0 + xxn. 4 MFMA. Panel 0 only.
__device__ __forceinline__ void score4(const char* sm, const float* xxs,
                                       int mlb, int mf, int h,
                                       const f16x8 b0[4], float s[16]) {
    f32x16v acc;
#pragma unroll
    for (int g2i = 0; g2i < 4; ++g2i) {
        f32x4v xv = *(const f32x4v*)&xxs[mlb + 4 * h + 8 * g2i];
#pragma unroll
        for (int q = 0; q < 4; ++q) acc[g2i * 4 + q] = xv[q];
    }
    __builtin_amdgcn_s_setprio(1);
#pragma unroll
    for (int kc = 0; kc < 4; ++kc) {
        int seg = kc * 2 + h;
        f16x8 a0 = __builtin_bit_cast(f16x8,
            *(const f32x4v*)(sm + seg * 4096 + (mlb + mf) * 16));
        acc = __builtin_amdgcn_mfma_f32_32x32x16_f16(a0, b0[kc], acc, 0, 0, 0);
    }
    __builtin_amdgcn_s_setprio(0);
#pragma unroll
    for (int r = 0; r < 16; ++r) s[r] = acc[r];
}

// 2-limb precise score (phase 2): 12 MFMA (acc3 dropped, validated r5).
__device__ __forceinline__ void score16(const char* sm, const float* xxs,
                                        int mlb, int mf, int h,
                                        const f16x8 b0[4], const f16x8 b1[4],
                                        float s[16]) {
    const float c12 = 1.f / 4096.f;
    f32x16v acc1, acc2;
#pragma unroll
    for (int g2i = 0; g2i < 4; ++g2i) {
        f32x4v xv = *(const f32x4v*)&xxs[mlb + 4 * h + 8 * g2i];
#pragma unroll
        for (int q = 0; q < 4; ++q) {
            acc1[g2i * 4 + q] = xv[q];
            acc2[g2i * 4 + q] = 0.f;
        }
    }
    __builtin_amdgcn_s_setprio(1);
#pragma unroll
    for (int kc = 0; kc < 4; ++kc) {
        int seg = kc * 2 + h;
        const char* pA = sm + seg * 4096 + (mlb + mf) * 16;
        f16x8 a0 = __builtin_bit_cast(f16x8, *(const f32x4v*)pA);
        f16x8 a1 = __builtin_bit_cast(f16x8, *(const f32x4v*)(pA + 32768));
        acc1 = __builtin_amdgcn_mfma_f32_32x32x16_f16(a0, b0[kc], acc1, 0, 0, 0);
        acc2 = __builtin_amdgcn_mfma_f32_32x32x16_f16(a0, b1[kc], acc2, 0, 0, 0);
        acc2 = __builtin_amdgcn_mfma_f32_32x32x16_f16(a1, b0[kc], acc2, 0, 0, 0);
    }
    __builtin_amdgcn_s_setprio(0);
#pragma unroll
    for (int r = 0; r < 16; ++r)
        s[r] = acc1[r] + acc2[r] * c12;
}

// ---------------- Fused pipeline: split | bar | scan+qg | bar | out ------------
// Normal (graph-capturable) launch. Grid 512 x 512 thr = exactly 2 blocks/CU.
// Scan section = FROZEN r10 k_topk byte-for-byte. Split reproduces r7's exact
// fp64 association (seg-ascending). Out = r10 batched-gather, 8 rows/wave.
// LDS: scan map as before; split overlays sred f64[512] @0; out overlays
// T[64][66] @0 (all dead across barriers).
__global__ __launch_bounds__(512, 4) void k_fused(const float* __restrict__ x,
                                                  const float* __restrict__ W,
                                                  unsigned short* p0g,
                                                  unsigned short* p1g,
                                                  float* xxn,
                                                  u64* bufg,
                                                  int* idxo,
                                                  float* qg,
                                                  float* __restrict__ out) {
    __shared__ __align__(16) char smem[67328];
    int b = blockIdx.x & 7, nt = blockIdx.x >> 3;
    int n0 = nt * 64;
    int tid = threadIdx.x;
    int w = tid >> 6, l = tid & 63, h = l >> 5, mf = l & 31;
    int cs = w >> 1, wg = w & 1;
    int rowl = wg * 32 + mf;
    int b8 = b * 8;
    f32x4v* g0 = (f32x4v*)p0g;
    f32x4v* g1 = (f32x4v*)p1g;
    float* Mp   = (float*)(smem + 32768);        // [64][129]
    float* xxs  = (float*)(smem + 65792);
    int*   cntp = (int*)(smem + 66816);
    float* T2p  = (float*)(smem + 67072);

    // ================= Split: this block's 64 m-columns =======================
    {
        int seg = tid >> 6, mcol = tid & 63;
        int m = n0 + mcol;
        const float* xb = x + (size_t)b * C_ * N_;
        double ss = 0.0;
        unsigned short h0[8], h1[8];
#pragma unroll
        for (int j = 0; j < 8; ++j) {
            float v = xb[(size_t)(seg * 8 + j) * N_ + m];
            ss += (double)v * (double)v;
            _Float16 a = (_Float16)v;
            float r = v - (float)a;
            _Float16 bq = (_Float16)(r * 4096.f);
            h0[j] = __builtin_bit_cast(unsigned short, a);
            h1[j] = __builtin_bit_cast(unsigned short, bq);
        }
        uint4 q0, q1;
        q0.x = h0[0] | (h0[1] << 16); q0.y = h0[2] | (h0[3] << 16);
        q0.z = h0[4] | (h0[5] << 16); q0.w = h0[6] | (h0[7] << 16);
        q1.x = h1[0] | (h1[1] << 16); q1.y = h1[2] | (h1[3] << 16);
        q1.z = h1[4] | (h1[5] << 16); q1.w = h1[6] | (h1[7] << 16);
        size_t o16 = (size_t)(b8 + seg) * N_ + m;
        ((uint4*)p0g)[o16] = q0;
        ((uint4*)p1g)[o16] = q1;
        double* sred = (double*)smem;
        sred[tid] = ss;
        __syncthreads();
        if (tid < 64) {
            double t = 0.0;
#pragma unroll
            for (int s = 0; s < 8; ++s) t += sred[s * 64 + tid];   // seg-ascending: r7 order
            xxn[b * N_ + n0 + tid] = (float)(-0.5 * t);
        }
    }
    gbarrier();   // p0/p1/xxn complete device-wide

    // B fragments (center rows), 2 limbs, register-resident
    f16x8 b0[4], b1[4];
#pragma unroll
    for (int kc = 0; kc < 4; ++kc) {
        int seg = kc * 2 + h;
        size_t gi = (size_t)(b8 + seg) * N_ + n0 + rowl;
        b0[kc] = __builtin_bit_cast(f16x8, g0[gi]);
        b1[kc] = __builtin_bit_cast(f16x8, g1[gi]);
    }

    // ================= Phase 1: approx scan -> per-row block maxima ===========
#pragma unroll 1
    for (int ch = 0; ch < 16; ++ch) {
        __syncthreads();
#pragma unroll
        for (int i = 0; i < 4; ++i) {
            int lin = i * 512 + tid;            // 0..2047
            int seg = lin >> 8, ml = lin & 255;
            gll16(g0 + ((size_t)(b8 + seg) * N_ + ch * 256 + ml),
                  smem + seg * 4096 + ml * 16);
        }
        if (tid < 256) xxs[tid] = xxn[b * N_ + ch * 256 + tid];
        __syncthreads();
#pragma unroll
        for (int t = 0; t < 2; ++t) {
            int mlb = cs * 64 + t * 32;
            float s[16];
            score4(smem, xxs, mlb, mf, h, b0, s);
            float m8[8];
#pragma unroll
            for (int r = 0; r < 8; ++r) m8[r] = fmaxf(s[r], s[r + 8]);
            float mx = fmaxf(fmaxf(fmaxf(m8[0], m8[1]), fmaxf(m8[2], m8[3])),
                             fmaxf(fmaxf(m8[4], m8[5]), fmaxf(m8[6], m8[7])));
            mx = fmaxf(mx, __shfl_xor(mx, 32));
            if (l < 32)
                Mp[rowl * 129 + ch * 8 + t * 4 + cs] = mx;
        }
    }

    // ================= Select: t* = 20th of 128 maxima per row ================
    __syncthreads();
    if (tid < 256) {                             // 4 lanes per row, top-8 each
        int row = tid >> 2, q = tid & 3;
        const float* mrow = Mp + row * 129 + q * 32;
        float v8[8];
#pragma unroll
        for (int j = 0; j < 8; ++j) v8[j] = -FLT_MAX;
#pragma unroll
        for (int i = 0; i < 32; ++i) {
            float v = mrow[i];
#pragma unroll
            for (int j = 7; j >= 1; --j) {
                bool c1 = v > v8[j - 1];
                float nv = c1 ? v8[j - 1] : v;
                v8[j] = (v > v8[j]) ? nv : v8[j];
            }
            v8[0] = fmaxf(v8[0], v);
        }
        float* lp = (float*)smem + row * 33 + q * 8;  // L overlay on pan0 (dead)
#pragma unroll
        for (int j = 0; j < 8; ++j) lp[j] = v8[j];
    }
    __syncthreads();
    if (tid < 64) {                              // 4-way merge to the 20th
        const float* lp = (const float*)smem + tid * 33;
        float hv0 = lp[0], hv1 = lp[8], hv2 = lp[16], hv3 = lp[24];
        int p0 = 0, p1 = 0, p2 = 0, p3 = 0;
        float tstar = -FLT_MAX;
        for (int k = 0; k < 20; ++k) {
            bool a = hv0 >= hv1; float ma = a ? hv0 : hv1; int sa = a ? 0 : 1;
            bool bb = hv2 >= hv3; float mb = bb ? hv2 : hv3; int sb = bb ? 2 : 3;
            bool c = ma >= mb; tstar = c ? ma : mb; int sl = c ? sa : sb;
            if (sl == 0) { ++p0; hv0 = (p0 < 8) ? lp[p0] : -FLT_MAX; }
            else if (sl == 1) { ++p1; hv1 = (p1 < 8) ? lp[8 + p1] : -FLT_MAX; }
            else if (sl == 2) { ++p2; hv2 = (p2 < 8) ? lp[16 + p2] : -FLT_MAX; }
            else { ++p3; hv3 = (p3 < 8) ? lp[24 + p3] : -FLT_MAX; }
        }
        T2p[tid] = tstar - MARGIN;
        cntp[tid] = 0;
    }
    __syncthreads();
    float T2r = T2p[rowl];

    // ================= Phase 2: precise re-scan + emit keys to global =========
#pragma unroll 1
    for (int ch = 0; ch < 16; ++ch) {
        __syncthreads();
#pragma unroll
        for (int i = 0; i < 8; ++i) {
            int lin = i * 512 + tid;            // 0..4095
            int panel = lin >> 11;
            int rem = lin & 2047;
            int seg = rem >> 8, ml = rem & 255;
            const f32x4v* src = panel ? g1 : g0;
            gll16(src + ((size_t)(b8 + seg) * N_ + ch * 256 + ml),
                  smem + panel * 32768 + seg * 4096 + ml * 16);
        }
        if (tid < 256) xxs[tid] = xxn[b * N_ + ch * 256 + tid];
        __syncthreads();
#pragma unroll
        for (int t = 0; t < 2; ++t) {
            int mlb = cs * 64 + t * 32;
            float s[16];
            score16(smem, xxs, mlb, mf, h, b0, b1, s);
            unsigned msk = 0;
#pragma unroll
            for (int r = 0; r < 16; ++r) msk |= (s[r] >= T2r) ? (1u << r) : 0u;
            int cb = ch * 256 + mlb + 4 * h;
            while (msk) {
                int r = __ffs(msk) - 1;
                msk &= msk - 1;
                int cand = cb + (r & 3) + 8 * (r >> 2);
                float sv = s[r];
                unsigned sb = __float_as_uint(sv);
                unsigned kk = (sv < 0.f) ? ~sb : (sb | 0x80000000u);
                int slot = atomicAdd(cntp + rowl, 1);
                if (slot < CAP)
                    bufg[((size_t)(b * N_ + n0 + rowl)) * CAP + slot] =
                        ((u64)kk << 32) | (unsigned)(~cand);
            }
        }
    }

    // ===== Phase 3: keys+Wl -> LDS; wave0 exact top-20 || waves run qg tail ====
    __syncthreads();
    u64*   keys = (u64*)(smem + 33536);          // 64 x 65 u64, ends at 66816
    float* Wl   = (float*)smem;                  // 64 x 129 f32 = 33024
#pragma unroll
    for (int i = 0; i < 8; ++i) {
        int p = i * 512 + tid;                   // 0..4095
        int row = p >> 6, slot = p & 63;
        int c_ = cntp[row]; c_ = (c_ > CAP) ? CAP : c_;
        u64 key = 0;
        if (slot < c_)
            key = bufg[((size_t)(b * N_ + n0 + row)) * CAP + slot];
        keys[row * (CAP + 1) + slot] = key;
    }
#pragma unroll
    for (int i = 0; i < 16; ++i) {
        int lin = i * 512 + tid;                 // 0..8191
        int c = lin & 63, o2 = lin >> 6;
        float wv;
        if (o2 < 64) wv = W[o2 * 128 + c];
        else { int o = o2 - 64; wv = W[o * 128 + 64 + c] - W[o * 128 + c]; }
        Wl[c * 129 + o2] = wv;
    }
    __syncthreads();   // keys copied out of bufg; bufg now dead for this block

    if (tid < 64) {    // wave 0: serial exact top-20 (waves 1-7 start qg tail)
        int c_ = cntp[tid]; c_ = (c_ > CAP) ? CAP : c_;
        u64* kp = keys + tid * (CAP + 1);
        int* op = idxo + ((size_t)b * N_ + n0 + tid) * K_;
        for (int k = 0; k < K_; ++k) {
            u64 best = 0; int bs = 0;
            for (int s2 = 0; s2 < c_; ++s2) {
                bool g = kp[s2] > best;
                best = g ? kp[s2] : best;
                bs = g ? s2 : bs;
            }
            op[k] = (int)(~(unsigned)best) & 0xFFF;
            kp[bs] = 0;
        }
    }

    // ---- qg tail: wave w computes qg rows n0+w*8 .. n0+w*8+8 (overlays own
    //      dead bufg). x read directly; Wl from LDS.
    {
        int u = l, g8 = w;
        const float* xb = x + (size_t)b * C_ * N_ + n0 + g8 * 8;
        float a0[8], a1[8];
#pragma unroll
        for (int j = 0; j < 8; ++j) { a0[j] = 0.f; a1[j] = 0.f; }
#pragma unroll 4
        for (int c = 0; c < 64; ++c) {
            float2 wv = *(const float2*)&Wl[c * 129 + 2 * u];
            float4 v0 = *(const float4*)&xb[(size_t)c * N_];
            float4 v1 = *(const float4*)&xb[(size_t)c * N_ + 4];
            a0[0] += wv.x * v0.x; a1[0] += wv.y * v0.x;
            a0[1] += wv.x * v0.y; a1[1] += wv.y * v0.y;
            a0[2] += wv.x * v0.z; a1[2] += wv.y * v0.z;
            a0[3] += wv.x * v0.w; a1[3] += wv.y * v0.w;
            a0[4] += wv.x * v1.x; a1[4] += wv.y * v1.x;
            a0[5] += wv.x * v1.y; a1[5] += wv.y * v1.y;
            a0[6] += wv.x * v1.z; a1[6] += wv.y * v1.z;
            a0[7] += wv.x * v1.w; a1[7] += wv.y * v1.w;
        }
#pragma unroll
        for (int j = 0; j < 8; ++j) {
            float2 o; o.x = a0[j]; o.y = a1[j];
            *(float2*)&qg[((size_t)b * N_ + n0 + g8 * 8 + j) * 128 + 2 * u] = o;
        }
    }
    gbarrier();   // all qg + idx complete device-wide

    // ================= Out: rows n0..n0+64 (r10 batched-gather body) ==========
    {
        float* T = (float*)smem;                 // [64][66] overlay (all dead)
        int ww = tid >> 6, o = tid & 63;
        const float* qgb = qg + (size_t)b * N_ * 128;
#pragma unroll 1
        for (int i = 0; i < 8; ++i) {
            int nl = ww * 8 + i;
            int n = n0 + nl;
            const int* ip = idxo + ((size_t)b * N_ + n) * K_;
            int iks[K_];
#pragma unroll
            for (int k = 0; k < K_; ++k) iks[k] = ip[k];      // wave-uniform batch
            float gv = qgb[(size_t)n * 128 + 64 + o];
            float hh[K_];
#pragma unroll
            for (int k = 0; k < K_; ++k)                      // 20 independent gathers
                hh[k] = qgb[(size_t)iks[k] * 128 + o];
#pragma unroll
            for (int k = 0; k < K_; ++k) {
                float v = hh[k] + gv;
                hh[k] = (v >= 0.f) ? v : 0.01f * v;
            }
            float m0 = fmaxf(fmaxf(fmaxf(hh[0], hh[1]), fmaxf(hh[2], hh[3])),
                             fmaxf(hh[4], hh[5]));
            float m1 = fmaxf(fmaxf(fmaxf(hh[6], hh[7]), fmaxf(hh[8], hh[9])),
                             fmaxf(hh[10], hh[11]));
            float m2 = fmaxf(fmaxf(fmaxf(hh[12], hh[13]), fmaxf(hh[14], hh[15])),
                             fmaxf(hh[16], hh[17]));
            float m3 = fmaxf(hh[18], hh[19]);
            T[nl * 66 + o] = fmaxf(fmaxf(m0, m1), fmaxf(m2, m3));
        }
        __syncthreads();
        int ow = tid >> 3, q = tid & 7;          // ow 0..63, q 0..7
        int nl = q * 8;
        float4 v0, v1;
        v0.x = T[(nl + 0) * 66 + ow]; v0.y = T[(nl + 1) * 66 + ow];
        v0.z = T[(nl + 2) * 66 + ow]; v0.w = T[(nl + 3) * 66 + ow];
        v1.x = T[(nl + 4) * 66 + ow]; v1.y = T[(nl + 5) * 66 + ow];
        v1.z = T[(nl + 6) * 66 + ow]; v1.w = T[(nl + 7) * 66 + ow];
        *(float4*)&out[((size_t)b * 64 + ow) * N_ + n0 + nl] = v0;
        *(float4*)&out[((size_t)b * 64 + ow) * N_ + n0 + nl + 4] = v1;
    }
}

extern "C" void kernel_launch(void* const* d_in, const int* in_sizes, int n_in,
                              void* d_out, int out_size, void* d_ws, size_t ws_size,
                              hipStream_t stream) {
    const float* x = (const float*)d_in[0];
    const float* W = (const float*)d_in[1];
    float* out = (float*)d_out;

    float*          xxn  = (float*)d_ws;
    int*            idx  = (int*)((char*)d_ws + OFF_IDX);
    float*          qg   = (float*)((char*)d_ws + OFF_QG);
    u64*            bufg = (u64*)((char*)d_ws + OFF_QG);   // per-block self-overlay
    unsigned short* p0   = (unsigned short*)((char*)d_ws + OFF_P0);
    unsigned short* p1   = (unsigned short*)((char*)d_ws + OFF_P1);

    k_fused<<<dim3(GRID_), dim3(512), 0, stream>>>(
        x, W, p0, p1, xxn, bufg, idx, qg, out);
}

// Round 14
// 206.938 us; speedup vs baseline: 1.4700x; 1.4700x over previous
//
#include <hip/hip_runtime.h>
#include <cfloat>

#define B_ 8
#define C_ 64
#define N_ 4096
#define K_ 20
#define MARGIN 0.08f
#define CAP 64

typedef float f32x4v  __attribute__((ext_vector_type(4)));
typedef float f32x16v __attribute__((ext_vector_type(16)));
typedef _Float16 f16x8 __attribute__((ext_vector_type(8)));
typedef unsigned long long u64;

// ws layout (bytes):
//   xxn : B*N floats (= -xx/2, fp64-accumulated)  @ 0
//   idx : B*N*20 ints                             @ 131072
//   qg  : B*N*128 floats [b][m][o2]               @ 2752512  (16 MB)
//         -- ALSO used (during k_topk) as bufg: B*N*CAP u64 = 16 MB exact.
//         Per-block self-aliasing overlay (validated r5).
//   P0  : [b][seg=c/8][m][j=c%8] f16 limb0        @ 19529728 (4 MB)
//   P1  : limb1 (scale 2^-12)                     @ 23724032 (4 MB)
#define OFF_IDX 131072
#define OFF_QG  2752512
#define OFF_P0  19529728
#define OFF_P1  23724032

// async global->LDS, 16B per lane. Per-wave LDS dst is uniform base + lane*16;
// global src is per-lane consecutive 16B. Validated rounds 1-10.
__device__ __forceinline__ void gll16(const void* g, void* l) {
    __builtin_amdgcn_global_load_lds(
        (const __attribute__((address_space(1))) unsigned int*)g,
        (__attribute__((address_space(3))) unsigned int*)l, 16, 0, 0);
}

// ---------------- Kernel 1: 2-limb fp16 split + (-xx/2) ----------------
// (round-7 validated: 8-way c-split, 16 waves/CU, LDS fp64 reduce)
__global__ __launch_bounds__(256) void k_split(const float* __restrict__ x,
                                               unsigned short* __restrict__ p0,
                                               unsigned short* __restrict__ p1,
                                               float* __restrict__ xxn) {
    __shared__ double sred[256];
    int b = blockIdx.x & 7, mt = blockIdx.x >> 3;
    int tid = threadIdx.x;
    int seg = tid >> 5, ml = tid & 31;
    int m = mt * 32 + ml;
    const float* xb = x + (size_t)b * C_ * N_;
    double ss = 0.0;
    unsigned short h0[8], h1[8];
#pragma unroll
    for (int j = 0; j < 8; ++j) {
        float v = xb[(size_t)(seg * 8 + j) * N_ + m];
        ss += (double)v * (double)v;
        _Float16 a = (_Float16)v;
        float r = v - (float)a;
        _Float16 bq = (_Float16)(r * 4096.f);
        h0[j] = __builtin_bit_cast(unsigned short, a);
        h1[j] = __builtin_bit_cast(unsigned short, bq);
    }
    uint4 q0, q1;
    q0.x = h0[0] | (h0[1] << 16); q0.y = h0[2] | (h0[3] << 16);
    q0.z = h0[4] | (h0[5] << 16); q0.w = h0[6] | (h0[7] << 16);
    q1.x = h1[0] | (h1[1] << 16); q1.y = h1[2] | (h1[3] << 16);
    q1.z = h1[4] | (h1[5] << 16); q1.w = h1[6] | (h1[7] << 16);
    size_t o16 = (size_t)(b * 8 + seg) * N_ + m;
    ((uint4*)p0)[o16] = q0;
    ((uint4*)p1)[o16] = q1;
    sred[tid] = ss;
    __syncthreads();
    if (tid < 32) {
        double t = 0.0;
#pragma unroll
        for (int s = 0; s < 8; ++s) t += sred[s * 32 + tid];
        xxn[b * N_ + mt * 32 + tid] = (float)(-0.5 * t);
    }
}

// 1-limb approx score (phase 1): s = A0·B0 + xxn. 4 MFMA. Panel 0 only.
__device__ __forceinline__ void score4(const char* sm, const float* xxs,
                                       int mlb, int mf, int h,
                                       const f16x8 b0[4], float s[16]) {
    f32x16v acc;
#pragma unroll
    for (int g2i = 0; g2i < 4; ++g2i) {
        f32x4v xv = *(const f32x4v*)&xxs[mlb + 4 * h + 8 * g2i];
#pragma unroll
        for (int q = 0; q < 4; ++q) acc[g2i * 4 + q] = xv[q];
    }
    __builtin_amdgcn_s_setprio(1);
#pragma unroll
    for (int kc = 0; kc < 4; ++kc) {
        int seg = kc * 2 + h;
        f16x8 a0 = __builtin_bit_cast(f16x8,
            *(const f32x4v*)(sm + seg * 4096 + (mlb + mf) * 16));
        acc = __builtin_amdgcn_mfma_f32_32x32x16_f16(a0, b0[kc], acc, 0, 0, 0);
    }
    __builtin_amdgcn_s_setprio(0);
#pragma unroll
    for (int r = 0; r < 16; ++r) s[r] = acc[r];
}

// 2-limb precise score (phase 2): 12 MFMA (acc3 dropped, validated r5:
// contribution ~2e-6, absmax unchanged).
__device__ __forceinline__ void score16(const char* sm, const float* xxs,
                                        int mlb, int mf, int h,
                                        const f16x8 b0[4], const f16x8 b1[4],
                                        float s[16]) {
    const float c12 = 1.f / 4096.f;
    f32x16v acc1, acc2;
#pragma unroll
    for (int g2i = 0; g2i < 4; ++g2i) {
        f32x4v xv = *(const f32x4v*)&xxs[mlb + 4 * h + 8 * g2i];
#pragma unroll
        for (int q = 0; q < 4; ++q) {
            acc1[g2i * 4 + q] = xv[q];
            acc2[g2i * 4 + q] = 0.f;
        }
    }
    __builtin_amdgcn_s_setprio(1);
#pragma unroll
    for (int kc = 0; kc < 4; ++kc) {
        int seg = kc * 2 + h;
        const char* pA = sm + seg * 4096 + (mlb + mf) * 16;
        f16x8 a0 = __builtin_bit_cast(f16x8, *(const f32x4v*)pA);
        f16x8 a1 = __builtin_bit_cast(f16x8, *(const f32x4v*)(pA + 32768));
        acc1 = __builtin_amdgcn_mfma_f32_32x32x16_f16(a0, b0[kc], acc1, 0, 0, 0);
        acc2 = __builtin_amdgcn_mfma_f32_32x32x16_f16(a0, b1[kc], acc2, 0, 0, 0);
        acc2 = __builtin_amdgcn_mfma_f32_32x32x16_f16(a1, b0[kc], acc2, 0, 0, 0);
    }
    __builtin_amdgcn_s_setprio(0);
#pragma unroll
    for (int r = 0; r < 16; ++r)
        s[r] = acc1[r] + acc2[r] * c12;
}

// ---------------- Kernel 2: kNN + fused qg tail (round-10, FROZEN) ------------
// 512 thr, 8 waves, 67KB LDS, 2 blocks/CU, gll16 staging, plain __syncthreads.
// r1/r2 (pipelining), r6 (occupancy), r8 (L2-direct), r9 (VALU trims),
// r13 (whole-pipeline fusion) all regressed or nulled: the scan is
// latency/barrier-structure-bound at ~145us with warm per-XCD L2 as a
// load-bearing ingredient.
// LDS: pan0 0..32768 | pan1/M 32768..65792 | xxs 65792..66816 |
//      cnt 66816..67072 | T2 67072..67328 | L overlay 0..8448 |
//      phase3: Wl 0..33024, keys 33536..66816
__global__ __launch_bounds__(512, 4) void k_topk(const unsigned short* __restrict__ p0g,
                                                 const unsigned short* __restrict__ p1g,
                                                 const float* __restrict__ xxn,
                                                 u64* bufg,
                                                 int* __restrict__ idxo,
                                                 const float* __restrict__ x,
                                                 const float* __restrict__ W,
                                                 float* qg) {
    __shared__ __align__(16) char smem[67328];
    int b = blockIdx.x & 7, nt = blockIdx.x >> 3;
    int n0 = nt * 64;
    int tid = threadIdx.x;
    int w = tid >> 6, l = tid & 63, h = l >> 5, mf = l & 31;
    int cs = w >> 1, wg = w & 1;
    int rowl = wg * 32 + mf;
    int b8 = b * 8;
    const f32x4v* g0 = (const f32x4v*)p0g;
    const f32x4v* g1 = (const f32x4v*)p1g;
    float* Mp   = (float*)(smem + 32768);        // [64][129]
    float* xxs  = (float*)(smem + 65792);
    int*   cntp = (int*)(smem + 66816);
    float* T2p  = (float*)(smem + 67072);

    // B fragments (center rows), 2 limbs, register-resident
    f16x8 b0[4], b1[4];
#pragma unroll
    for (int kc = 0; kc < 4; ++kc) {
        int seg = kc * 2 + h;
        size_t gi = (size_t)(b8 + seg) * N_ + n0 + rowl;
        b0[kc] = __builtin_bit_cast(f16x8, g0[gi]);
        b1[kc] = __builtin_bit_cast(f16x8, g1[gi]);
    }

    // ================= Phase 1: approx scan -> per-row block maxima ===========
#pragma unroll 1
    for (int ch = 0; ch < 16; ++ch) {
        __syncthreads();
#pragma unroll
        for (int i = 0; i < 4; ++i) {
            int lin = i * 512 + tid;            // 0..2047
            int seg = lin >> 8, ml = lin & 255;
            gll16(g0 + ((size_t)(b8 + seg) * N_ + ch * 256 + ml),
                  smem + seg * 4096 + ml * 16);
        }
        if (tid < 256) xxs[tid] = xxn[b * N_ + ch * 256 + tid];
        __syncthreads();
#pragma unroll
        for (int t = 0; t < 2; ++t) {
            int mlb = cs * 64 + t * 32;
            float s[16];
            score4(smem, xxs, mlb, mf, h, b0, s);
            float m8[8];
#pragma unroll
            for (int r = 0; r < 8; ++r) m8[r] = fmaxf(s[r], s[r + 8]);
            float mx = fmaxf(fmaxf(fmaxf(m8[0], m8[1]), fmaxf(m8[2], m8[3])),
                             fmaxf(fmaxf(m8[4], m8[5]), fmaxf(m8[6], m8[7])));
            mx = fmaxf(mx, __shfl_xor(mx, 32));
            if (l < 32)
                Mp[rowl * 129 + ch * 8 + t * 4 + cs] = mx;
        }
    }

    // ================= Select: t* = 20th of 128 maxima per row ================
    __syncthreads();
    if (tid < 256) {                             // 4 lanes per row, top-8 each
        int row = tid >> 2, q = tid & 3;
        const float* mrow = Mp + row * 129 + q * 32;
        float v8[8];
#pragma unroll
        for (int j = 0; j < 8; ++j) v8[j] = -FLT_MAX;
#pragma unroll
        for (int i = 0; i < 32; ++i) {
            float v = mrow[i];
#pragma unroll
            for (int j = 7; j >= 1; --j) {
                bool c1 = v > v8[j - 1];
                float nv = c1 ? v8[j - 1] : v;
                v8[j] = (v > v8[j]) ? nv : v8[j];
            }
            v8[0] = fmaxf(v8[0], v);
        }
        float* lp = (float*)smem + row * 33 + q * 8;  // L overlay on pan0 (dead)
#pragma unroll
        for (int j = 0; j < 8; ++j) lp[j] = v8[j];
    }
    __syncthreads();
    if (tid < 64) {                              // 4-way merge to the 20th
        const float* lp = (const float*)smem + tid * 33;
        float hv0 = lp[0], hv1 = lp[8], hv2 = lp[16], hv3 = lp[24];
        int p0 = 0, p1 = 0, p2 = 0, p3 = 0;
        float tstar = -FLT_MAX;
        for (int k = 0; k < 20; ++k) {
            bool a = hv0 >= hv1; float ma = a ? hv0 : hv1; int sa = a ? 0 : 1;
            bool bb = hv2 >= hv3; float mb = bb ? hv2 : hv3; int sb = bb ? 2 : 3;
            bool c = ma >= mb; tstar = c ? ma : mb; int sl = c ? sa : sb;
            if (sl == 0) { ++p0; hv0 = (p0 < 8) ? lp[p0] : -FLT_MAX; }
            else if (sl == 1) { ++p1; hv1 = (p1 < 8) ? lp[8 + p1] : -FLT_MAX; }
            else if (sl == 2) { ++p2; hv2 = (p2 < 8) ? lp[16 + p2] : -FLT_MAX; }
            else { ++p3; hv3 = (p3 < 8) ? lp[24 + p3] : -FLT_MAX; }
        }
        T2p[tid] = tstar - MARGIN;
        cntp[tid] = 0;
    }
    __syncthreads();
    float T2r = T2p[rowl];

    // ================= Phase 2: precise re-scan + emit keys to global =========
#pragma unroll 1
    for (int ch = 0; ch < 16; ++ch) {
        __syncthreads();
#pragma unroll
        for (int i = 0; i < 8; ++i) {
            int lin = i * 512 + tid;            // 0..4095
            int panel = lin >> 11;
            int rem = lin & 2047;
            int seg = rem >> 8, ml = rem & 255;
            const f32x4v* src = panel ? g1 : g0;
            gll16(src + ((size_t)(b8 + seg) * N_ + ch * 256 + ml),
                  smem + panel * 32768 + seg * 4096 + ml * 16);
        }
        if (tid < 256) xxs[tid] = xxn[b * N_ + ch * 256 + tid];
        __syncthreads();
#pragma unroll
        for (int t = 0; t < 2; ++t) {
            int mlb = cs * 64 + t * 32;
            float s[16];
            score16(smem, xxs, mlb, mf, h, b0, b1, s);
            unsigned msk = 0;
#pragma unroll
            for (int r = 0; r < 16; ++r) msk |= (s[r] >= T2r) ? (1u << r) : 0u;
            int cb = ch * 256 + mlb + 4 * h;
            while (msk) {
                int r = __ffs(msk) - 1;
                msk &= msk - 1;
                int cand = cb + (r & 3) + 8 * (r >> 2);
                float sv = s[r];
                unsigned sb = __float_as_uint(sv);
                unsigned kk = (sv < 0.f) ? ~sb : (sb | 0x80000000u);
                int slot = atomicAdd(cntp + rowl, 1);
                if (slot < CAP)
                    bufg[((size_t)(b * N_ + n0 + rowl)) * CAP + slot] =
                        ((u64)kk << 32) | (unsigned)(~cand);
            }
        }
    }

    // ===== Phase 3: keys+Wl -> LDS; wave0 exact top-20 || waves run qg tail ====
    __syncthreads();
    u64*   keys = (u64*)(smem + 33536);          // 64 x 65 u64, ends at 66816
    float* Wl   = (float*)smem;                  // 64 x 129 f32 = 33024
#pragma unroll
    for (int i = 0; i < 8; ++i) {
        int p = i * 512 + tid;                   // 0..4095
        int row = p >> 6, slot = p & 63;
        int c_ = cntp[row]; c_ = (c_ > CAP) ? CAP : c_;
        u64 key = 0;
        if (slot < c_)
            key = bufg[((size_t)(b * N_ + n0 + row)) * CAP + slot];
        keys[row * (CAP + 1) + slot] = key;
    }
#pragma unroll
    for (int i = 0; i < 16; ++i) {
        int lin = i * 512 + tid;                 // 0..8191
        int c = lin & 63, o2 = lin >> 6;
        float wv;
        if (o2 < 64) wv = W[o2 * 128 + c];
        else { int o = o2 - 64; wv = W[o * 128 + 64 + c] - W[o * 128 + c]; }
        Wl[c * 129 + o2] = wv;
    }
    __syncthreads();   // keys copied out of bufg; bufg now dead for this block

    if (tid < 64) {    // wave 0: serial exact top-20 (waves 1-7 start qg tail)
        int c_ = cntp[tid]; c_ = (c_ > CAP) ? CAP : c_;
        u64* kp = keys + tid * (CAP + 1);
        int* op = idxo + ((size_t)b * N_ + n0 + tid) * K_;
        for (int k = 0; k < K_; ++k) {
            u64 best = 0; int bs = 0;
            for (int s2 = 0; s2 < c_; ++s2) {
                bool g = kp[s2] > best;
                best = g ? kp[s2] : best;
                bs = g ? s2 : bs;
            }
            op[k] = (int)(~(unsigned)best) & 0xFFF;
            kp[bs] = 0;
        }
    }

    // ---- qg tail: wave w computes qg rows n0+w*8 .. n0+w*8+8 (overlays own
    //      dead bufg). x read directly (uniform 32B/c, L1-hot); Wl from LDS.
    {
        int u = l, g8 = w;
        const float* xb = x + (size_t)b * C_ * N_ + n0 + g8 * 8;
        float a0[8], a1[8];
#pragma unroll
        for (int j = 0; j < 8; ++j) { a0[j] = 0.f; a1[j] = 0.f; }
#pragma unroll 4
        for (int c = 0; c < 64; ++c) {
            float2 wv = *(const float2*)&Wl[c * 129 + 2 * u];
            float4 v0 = *(const float4*)&xb[(size_t)c * N_];
            float4 v1 = *(const float4*)&xb[(size_t)c * N_ + 4];
            a0[0] += wv.x * v0.x; a1[0] += wv.y * v0.x;
            a0[1] += wv.x * v0.y; a1[1] += wv.y * v0.y;
            a0[2] += wv.x * v0.z; a1[2] += wv.y * v0.z;
            a0[3] += wv.x * v0.w; a1[3] += wv.y * v0.w;
            a0[4] += wv.x * v1.x; a1[4] += wv.y * v1.x;
            a0[5] += wv.x * v1.y; a1[5] += wv.y * v1.y;
            a0[6] += wv.x * v1.z; a1[6] += wv.y * v1.z;
            a0[7] += wv.x * v1.w; a1[7] += wv.y * v1.w;
        }
#pragma unroll
        for (int j = 0; j < 8; ++j) {
            float2 o; o.x = a0[j]; o.y = a1[j];
            *(float2*)&qg[((size_t)b * N_ + n0 + g8 * 8 + j) * 128 + 2 * u] = o;
        }
    }
}

// ---------------- Kernel 3: out = max_k leaky(q[ik][o] + g[n][o]) ----------------
// (round-10 validated: 2048 blocks, batched index loads, 20 independent
// gathers in flight, pairwise fmax tree)
__global__ __launch_bounds__(256) void k_out(const float* __restrict__ qg,
                                             const int* __restrict__ idxi,
                                             float* __restrict__ out) {
    __shared__ float T[16][66];
    int b = blockIdx.x & 7, nt = blockIdx.x >> 3;
    int n0 = nt * 16;
    int tid = threadIdx.x;
    int w = tid >> 6, o = tid & 63;
    const float* qgb = qg + (size_t)b * N_ * 128;
    for (int i = 0; i < 4; ++i) {
        int nl = w * 4 + i;
        int n = n0 + nl;
        const int* ip = idxi + ((size_t)b * N_ + n) * K_;
        int iks[K_];
#pragma unroll
        for (int k = 0; k < K_; ++k) iks[k] = ip[k];      // wave-uniform batch
        float gv = qgb[(size_t)n * 128 + 64 + o];
        float hh[K_];
#pragma unroll
        for (int k = 0; k < K_; ++k)                      // 20 independent gathers
            hh[k] = qgb[(size_t)iks[k] * 128 + o];
#pragma unroll
        for (int k = 0; k < K_; ++k) {
            float v = hh[k] + gv;
            hh[k] = (v >= 0.f) ? v : 0.01f * v;
        }
        // pairwise max tree (depth 5, no serial 20-chain)
        float m0 = fmaxf(fmaxf(fmaxf(hh[0], hh[1]), fmaxf(hh[2], hh[3])),
                         fmaxf(hh[4], hh[5]));
        float m1 = fmaxf(fmaxf(fmaxf(hh[6], hh[7]), fmaxf(hh[8], hh[9])),
                         fmaxf(hh[10], hh[11]));
        float m2 = fmaxf(fmaxf(fmaxf(hh[12], hh[13]), fmaxf(hh[14], hh[15])),
                         fmaxf(hh[16], hh[17]));
        float m3 = fmaxf(hh[18], hh[19]);
        T[nl][o] = fmaxf(fmaxf(m0, m1), fmaxf(m2, m3));
    }
    __syncthreads();
    int ow = tid >> 2, q = tid & 3;
    {
        int nl = q * 4;
        float4 v;
        v.x = T[nl + 0][ow]; v.y = T[nl + 1][ow];
        v.z = T[nl + 2][ow]; v.w = T[nl + 3][ow];
        *(float4*)&out[((size_t)b * 64 + ow) * N_ + n0 + nl] = v;
    }
}

extern "C" void kernel_launch(void* const* d_in, const int* in_sizes, int n_in,
                              void* d_out, int out_size, void* d_ws, size_t ws_size,
                              hipStream_t stream) {
    const float* x = (const float*)d_in[0];
    const float* W = (const float*)d_in[1];
    float* out = (float*)d_out;

    float*          xxn  = (float*)d_ws;
    int*            idx  = (int*)((char*)d_ws + OFF_IDX);
    float*          qg   = (float*)((char*)d_ws + OFF_QG);
    u64*            bufg = (u64*)((char*)d_ws + OFF_QG);   // per-block self-overlay
    unsigned short* p0   = (unsigned short*)((char*)d_ws + OFF_P0);
    unsigned short* p1   = (unsigned short*)((char*)d_ws + OFF_P1);

    k_split<<<dim3(1024), dim3(256), 0, stream>>>(x, p0, p1, xxn);
    k_topk <<<dim3(512), dim3(512), 0, stream>>>(p0, p1, xxn, bufg, idx, x, W, qg);
    k_out  <<<dim3(2048), dim3(256), 0, stream>>>(qg, idx, out);
}